// Round 1
// baseline (5320.978 us; speedup 1.0000x reference)
//
#include <hip/hip_runtime.h>
#include <cmath>

// Problem constants
// B=32, S=512, T=64, IN=512, H=512, L=2, HC=4, OUT=512

__device__ __forceinline__ float sigmoidf_(float x) { return 1.f / (1.f + __expf(-x)); }

__device__ __forceinline__ float wave_sum(float v) {
#pragma unroll
  for (int m = 1; m < 64; m <<= 1) v += __shfl_xor(v, m, 64);
  return v;
}
__device__ __forceinline__ float wave_max(float v) {
#pragma unroll
  for (int m = 1; m < 64; m <<= 1) v = fmaxf(v, __shfl_xor(v, m, 64));
  return v;
}
__device__ __forceinline__ void ld8(const float* __restrict__ p, float* d) {
  float4 v0 = *(const float4*)p, v1 = *(const float4*)(p + 4);
  d[0]=v0.x; d[1]=v0.y; d[2]=v0.z; d[3]=v0.w; d[4]=v1.x; d[5]=v1.y; d[6]=v1.z; d[7]=v1.w;
}

// ---- init state: h0,h1 <- final_hiddens ; c0,c1 <- 0 -------------------------
__global__ void k_init(const float* __restrict__ fh, float* h0, float* h1, float* c0, float* c1) {
  int i = blockIdx.x * 256 + threadIdx.x;  // 16384
  h0[i] = fh[i]; h1[i] = fh[16384 + i]; c0[i] = 0.f; c1[i] = 0.f;
}

// ---- hid_proj[r][n] = sum_k hiddens[r][k] * Wa1[n][512+k]  (r in [0,16384)) --
__global__ void k_hidproj(const float* __restrict__ hid, const float* __restrict__ Wa1,
                          float* __restrict__ hp) {
  __shared__ float As[64][33];
  __shared__ float Bs[64][33];
  int tid = threadIdx.x;
  int r0 = blockIdx.x * 64;   // 256 tiles
  int n0 = blockIdx.y * 64;   // 8 tiles
  int tm = (tid >> 4) << 2;
  int tn = (tid & 15) << 2;
  int lr = tid >> 2, lk = (tid & 3) << 3;
  float acc[4][4] = {};
  for (int k0 = 0; k0 < 512; k0 += 32) {
    float4 a0 = *(const float4*)&hid[(r0 + lr) * 512 + k0 + lk];
    float4 a1 = *(const float4*)&hid[(r0 + lr) * 512 + k0 + lk + 4];
    float4 b0 = *(const float4*)&Wa1[(n0 + lr) * 1024 + 512 + k0 + lk];
    float4 b1 = *(const float4*)&Wa1[(n0 + lr) * 1024 + 512 + k0 + lk + 4];
    __syncthreads();
    As[lr][lk+0]=a0.x; As[lr][lk+1]=a0.y; As[lr][lk+2]=a0.z; As[lr][lk+3]=a0.w;
    As[lr][lk+4]=a1.x; As[lr][lk+5]=a1.y; As[lr][lk+6]=a1.z; As[lr][lk+7]=a1.w;
    Bs[lr][lk+0]=b0.x; Bs[lr][lk+1]=b0.y; Bs[lr][lk+2]=b0.z; Bs[lr][lk+3]=b0.w;
    Bs[lr][lk+4]=b1.x; Bs[lr][lk+5]=b1.y; Bs[lr][lk+6]=b1.z; Bs[lr][lk+7]=b1.w;
    __syncthreads();
#pragma unroll 8
    for (int kk = 0; kk < 32; kk++) {
      float av[4], bv[4];
#pragma unroll
      for (int i = 0; i < 4; i++) av[i] = As[tm + i][kk];
#pragma unroll
      for (int j = 0; j < 4; j++) bv[j] = Bs[tn + j][kk];
#pragma unroll
      for (int i = 0; i < 4; i++)
#pragma unroll
        for (int j = 0; j < 4; j++) acc[i][j] += av[i] * bv[j];
    }
  }
#pragma unroll
  for (int i = 0; i < 4; i++) {
    float4 v = make_float4(acc[i][0], acc[i][1], acc[i][2], acc[i][3]);
    *(float4*)&hp[(r0 + tm + i) * 512 + n0 + tn] = v;
  }
}

// ---- q[b][h] = sum_k h1[b][k] * Wa1[h][k]  (dup-projection, NO bias) --------
__global__ void k_q(const float* __restrict__ h1, const float* __restrict__ Wa1,
                    float* __restrict__ q) {
  int w = threadIdx.x >> 6, l = threadIdx.x & 63;
  int idx = (blockIdx.x << 2) + w;  // 16384
  int b = idx >> 9, hh = idx & 511;
  const float* xr = h1 + b * 512;
  const float* wr = Wa1 + hh * 1024;
  float acc = 0.f;
#pragma unroll
  for (int i = 0; i < 8; i++) acc += xr[l + (i << 6)] * wr[l + (i << 6)];
  acc = wave_sum(acc);
  if (l == 0) q[idx] = acc;
}

// ---- scores[b][k][s] = relu( Wa2 @ relu(mask*q + hp + ba1) + ba2 ) ----------
__global__ void k_scores(const float* __restrict__ hp, const float* __restrict__ q,
                         const float* __restrict__ ba1, const float* __restrict__ Wa2,
                         const float* __restrict__ ba2, const int* __restrict__ lengths,
                         float* __restrict__ scores) {
  int w = threadIdx.x >> 6, l = threadIdx.x & 63;
  int row = (blockIdx.x << 2) + w;  // 16384 = b*512+s
  int b = row >> 9, s = row & 511;
  int kb = l << 3;
  float wv[4][8];
#pragma unroll
  for (int k = 0; k < 4; k++) ld8(&Wa2[k * 512 + kb], wv[k]);
  float bb[8]; ld8(&ba1[kb], bb);
  float qv[8]; ld8(&q[b * 512 + kb], qv);
  float hv[8]; ld8(&hp[row * 512 + kb], hv);
  float m = (s < lengths[b]) ? 1.f : 0.f;
  float sc[4] = {0.f, 0.f, 0.f, 0.f};
#pragma unroll
  for (int j = 0; j < 8; j++) {
    float a = fmaxf(hv[j] + m * qv[j] + bb[j], 0.f);
    sc[0] += wv[0][j] * a; sc[1] += wv[1][j] * a;
    sc[2] += wv[2][j] * a; sc[3] += wv[3][j] * a;
  }
#pragma unroll
  for (int k = 0; k < 4; k++) sc[k] = wave_sum(sc[k]);
  if (l == 0) {
#pragma unroll
    for (int k = 0; k < 4; k++) scores[(b * 4 + k) * 512 + s] = fmaxf(sc[k] + ba2[k], 0.f);
  }
}

// ---- softmax over s (per b,k) + partial context sums over half the s-range --
__global__ void __launch_bounds__(512) k_smcvec(const float* __restrict__ scores,
                                                const float* __restrict__ hiddens,
                                                float* __restrict__ cvp) {
  __shared__ float smx[512 * 4];  // [s][k]
  __shared__ float red[8];        // {max, inv_sum} per k
  int b = blockIdx.x, sc = blockIdx.y;
  int t = threadIdx.x;
#pragma unroll
  for (int k = 0; k < 4; k++) smx[t * 4 + k] = scores[(b * 4 + k) * 512 + t];
  __syncthreads();
  if (t < 256) {  // waves 0..3: wave w handles k = w
    int w = t >> 6, l = t & 63;
    float vals[8];
    float mx = -1e30f;
#pragma unroll
    for (int i = 0; i < 8; i++) { vals[i] = smx[(l * 8 + i) * 4 + w]; mx = fmaxf(mx, vals[i]); }
    mx = wave_max(mx);
    float sum = 0.f;
#pragma unroll
    for (int i = 0; i < 8; i++) sum += __expf(vals[i] - mx);
    sum = wave_sum(sum);
    if (l == 0) { red[w * 2] = mx; red[w * 2 + 1] = 1.f / sum; }
  }
  __syncthreads();
  {
    float4 v = *(float4*)&smx[t * 4];
    v.x = __expf(v.x - red[0]) * red[1];
    v.y = __expf(v.y - red[2]) * red[3];
    v.z = __expf(v.z - red[4]) * red[5];
    v.w = __expf(v.w - red[6]) * red[7];
    *(float4*)&smx[t * 4] = v;
  }
  __syncthreads();
  float acc[4] = {0.f, 0.f, 0.f, 0.f};
  int s0 = sc * 256;
  for (int s = s0; s < s0 + 256; s++) {
    float hvv = hiddens[(b * 512 + s) * 512 + t];
    float4 p = *(const float4*)&smx[s * 4];
    acc[0] += p.x * hvv; acc[1] += p.y * hvv; acc[2] += p.z * hvv; acc[3] += p.w * hvv;
  }
#pragma unroll
  for (int k = 0; k < 4; k++) cvp[(sc * 32 + b) * 2048 + k * 512 + t] = acc[k];
}

// ---- xcat0[b][0:512]=input_t, [512:2560]=cvec(sum parts), [2560:3072]=h0 ----
__global__ void k_buildx0(const float* __restrict__ inputs, const float* __restrict__ cvp,
                          const float* __restrict__ h0, int t, float* __restrict__ xcat0) {
  int idx = blockIdx.x * 256 + threadIdx.x;  // 98304
  int b = idx / 3072, k = idx % 3072;
  float v;
  if (k < 512) v = inputs[(b * 64 + t) * 512 + k];
  else if (k < 2560) { int kc = k - 512; v = cvp[b * 2048 + kc] + cvp[(32 + b) * 2048 + kc]; }
  else v = h0[b * 512 + (k - 2560)];
  xcat0[idx] = v;
}

// ---- skinny GEMM with k-split: part[split][b][j] = sum_k x[b][k]*W(j,k) -----
// W(j,k) = k<kbound ? W1[j][k] : W2[j][k-kbound]
__global__ void k_skinny(const float* __restrict__ x, int K,
                         const float* __restrict__ W1, int ld1,
                         const float* __restrict__ W2, int ld2, int kbound,
                         int chunks_per_split, float* __restrict__ part, int J) {
  __shared__ float xs[32][65];
  __shared__ float ws[64][65];
  int tid = threadIdx.x;
  int j0 = blockIdx.x << 6;
  int jl = (tid & 31) << 1;
  int bl = (tid >> 5) << 2;
  int lb = tid >> 3, lk = (tid & 7) << 3;
  int lj = tid >> 2, lwk = (tid & 3) << 4;
  float acc[4][2] = {};
  for (int c = 0; c < chunks_per_split; c++) {
    int k0 = (blockIdx.y * chunks_per_split + c) << 6;
    float4 xv0 = *(const float4*)&x[lb * K + k0 + lk];
    float4 xv1 = *(const float4*)&x[lb * K + k0 + lk + 4];
    const float* Wp = (k0 < kbound) ? (W1 + (j0 + lj) * ld1 + k0)
                                    : (W2 + (j0 + lj) * ld2 + (k0 - kbound));
    float4 wv0 = *(const float4*)&Wp[lwk];
    float4 wv1 = *(const float4*)&Wp[lwk + 4];
    float4 wv2 = *(const float4*)&Wp[lwk + 8];
    float4 wv3 = *(const float4*)&Wp[lwk + 12];
    __syncthreads();
    xs[lb][lk+0]=xv0.x; xs[lb][lk+1]=xv0.y; xs[lb][lk+2]=xv0.z; xs[lb][lk+3]=xv0.w;
    xs[lb][lk+4]=xv1.x; xs[lb][lk+5]=xv1.y; xs[lb][lk+6]=xv1.z; xs[lb][lk+7]=xv1.w;
    ws[lj][lwk+0]=wv0.x; ws[lj][lwk+1]=wv0.y; ws[lj][lwk+2]=wv0.z; ws[lj][lwk+3]=wv0.w;
    ws[lj][lwk+4]=wv1.x; ws[lj][lwk+5]=wv1.y; ws[lj][lwk+6]=wv1.z; ws[lj][lwk+7]=wv1.w;
    ws[lj][lwk+8]=wv2.x; ws[lj][lwk+9]=wv2.y; ws[lj][lwk+10]=wv2.z; ws[lj][lwk+11]=wv2.w;
    ws[lj][lwk+12]=wv3.x; ws[lj][lwk+13]=wv3.y; ws[lj][lwk+14]=wv3.z; ws[lj][lwk+15]=wv3.w;
    __syncthreads();
#pragma unroll 16
    for (int kk = 0; kk < 64; kk++) {
      float w0 = ws[jl][kk], w1 = ws[jl + 1][kk];
      float x0 = xs[bl][kk], x1 = xs[bl + 1][kk], x2 = xs[bl + 2][kk], x3 = xs[bl + 3][kk];
      acc[0][0] += x0 * w0; acc[0][1] += x0 * w1;
      acc[1][0] += x1 * w0; acc[1][1] += x1 * w1;
      acc[2][0] += x2 * w0; acc[2][1] += x2 * w1;
      acc[3][0] += x3 * w0; acc[3][1] += x3 * w1;
    }
  }
#pragma unroll
  for (int i = 0; i < 4; i++) {
    int r = (blockIdx.y * 32 + bl + i) * J + j0 + jl;
    part[r] = acc[i][0]; part[r + 1] = acc[i][1];
  }
}

// ---- LSTM cell 0 epilogue: reduce k-splits, activations, build xcat1 --------
__global__ void k_act0(const float* __restrict__ part, const float* __restrict__ b_ih,
                       const float* __restrict__ b_hh, float* __restrict__ cst,
                       float* __restrict__ hst, const float* __restrict__ h1_old,
                       float* __restrict__ xcat1) {
  int idx = blockIdx.x * 256 + threadIdx.x;  // 16384
  int b = idx >> 9, hh = idx & 511;
  float g[4];
#pragma unroll
  for (int gi = 0; gi < 4; gi++) {
    int j = gi * 512 + hh;
    float v = b_ih[j] + b_hh[j];
#pragma unroll
    for (int sp = 0; sp < 8; sp++) v += part[(sp * 32 + b) * 2048 + j];
    g[gi] = v;
  }
  float i_ = sigmoidf_(g[0]), f_ = sigmoidf_(g[1]), gg = tanhf(g[2]), o_ = sigmoidf_(g[3]);
  float cn = f_ * cst[idx] + i_ * gg;
  float hn = o_ * tanhf(cn);
  cst[idx] = cn; hst[idx] = hn;
  xcat1[b * 1024 + hh] = hn;
  xcat1[b * 1024 + 512 + hh] = h1_old[idx];
}

// ---- LSTM cell 1 epilogue + build xo = [h1_new | cvec] ----------------------
__global__ void k_act1(const float* __restrict__ part, const float* __restrict__ b_ih,
                       const float* __restrict__ b_hh, float* __restrict__ cst,
                       float* __restrict__ hst, const float* __restrict__ xcat0,
                       float* __restrict__ xo) {
  int idx = blockIdx.x * 256 + threadIdx.x;  // 16384
  int b = idx >> 9, hh = idx & 511;
  float g[4];
#pragma unroll
  for (int gi = 0; gi < 4; gi++) {
    int j = gi * 512 + hh;
    float v = b_ih[j] + b_hh[j];
#pragma unroll
    for (int sp = 0; sp < 8; sp++) v += part[(sp * 32 + b) * 2048 + j];
    g[gi] = v;
  }
  float i_ = sigmoidf_(g[0]), f_ = sigmoidf_(g[1]), gg = tanhf(g[2]), o_ = sigmoidf_(g[3]);
  float cn = f_ * cst[idx] + i_ * gg;
  float hn = o_ * tanhf(cn);
  cst[idx] = cn; hst[idx] = hn;
  xo[b * 2560 + hh] = hn;
#pragma unroll
  for (int i = 0; i < 4; i++) {
    int kc = hh * 4 + i;
    xo[b * 2560 + 512 + kc] = xcat0[b * 3072 + 512 + kc];  // cvec already summed there
  }
}

// ---- o1[b][j] = relu(xo . Wo1[j] + bo1[j])  (wave per output, K=2560) -------
__global__ void k_o1(const float* __restrict__ xo, const float* __restrict__ Wo1,
                     const float* __restrict__ bo1, float* __restrict__ o1) {
  int w = threadIdx.x >> 6, l = threadIdx.x & 63;
  int idx = (blockIdx.x << 2) + w;  // 16384
  int b = idx >> 9, jj = idx & 511;
  const float* xr = xo + b * 2560;
  const float* wr = Wo1 + jj * 2560;
  float acc = 0.f;
#pragma unroll 8
  for (int i = l; i < 2560; i += 64) acc += xr[i] * wr[i];
  acc = wave_sum(acc);
  if (l == 0) o1[idx] = fmaxf(acc + bo1[jj], 0.f);
}

// ---- out[b][t][j] = tanh(o1 . Wo2[j] + bo2[j])  (wave per output, K=512) ----
__global__ void k_out(const float* __restrict__ o1, const float* __restrict__ Wo2,
                      const float* __restrict__ bo2, float* __restrict__ outp, int t) {
  int w = threadIdx.x >> 6, l = threadIdx.x & 63;
  int idx = (blockIdx.x << 2) + w;  // 16384
  int b = idx >> 9, jj = idx & 511;
  const float* xr = o1 + b * 512;
  const float* wr = Wo2 + jj * 512;
  float acc = 0.f;
#pragma unroll
  for (int i = 0; i < 8; i++) acc += xr[l + (i << 6)] * wr[l + (i << 6)];
  acc = wave_sum(acc);
  if (l == 0) outp[(b * 64 + t) * 512 + jj] = tanhf(acc + bo2[jj]);
}

extern "C" void kernel_launch(void* const* d_in, const int* in_sizes, int n_in,
                              void* d_out, int out_size, void* d_ws, size_t ws_size,
                              hipStream_t stream) {
  const float* inputs  = (const float*)d_in[0];
  const int*   lengths = (const int*)d_in[1];
  const float* fh      = (const float*)d_in[2];
  const float* hiddens = (const float*)d_in[3];
  const float* Wa1     = (const float*)d_in[6];
  const float* ba1     = (const float*)d_in[7];
  const float* Wa2     = (const float*)d_in[8];
  const float* ba2     = (const float*)d_in[9];
  const float* W_ih0   = (const float*)d_in[10];
  const float* W_hh0   = (const float*)d_in[11];
  const float* b_ih0   = (const float*)d_in[12];
  const float* b_hh0   = (const float*)d_in[13];
  const float* W_ih1   = (const float*)d_in[14];
  const float* W_hh1   = (const float*)d_in[15];
  const float* b_ih1   = (const float*)d_in[16];
  const float* b_hh1   = (const float*)d_in[17];
  const float* Wo1     = (const float*)d_in[18];
  const float* bo1     = (const float*)d_in[19];
  const float* Wo2     = (const float*)d_in[20];
  const float* bo2     = (const float*)d_in[21];
  float* outp = (float*)d_out;

  float* p = (float*)d_ws;
  float* hp     = p; p += 16384 * 512;   // 8388608
  float* q      = p; p += 16384;
  float* scores = p; p += 65536;
  float* cvp    = p; p += 2 * 65536;
  float* h0     = p; p += 16384;
  float* c0     = p; p += 16384;
  float* h1     = p; p += 16384;
  float* c1     = p; p += 16384;
  float* xcat0  = p; p += 32 * 3072;
  float* xcat1  = p; p += 32 * 1024;
  float* xo     = p; p += 32 * 2560;
  float* part   = p; p += 8 * 32 * 2048;
  float* o1b    = p; p += 16384;

  k_init<<<64, 256, 0, stream>>>(fh, h0, h1, c0, c1);
  k_hidproj<<<dim3(256, 8), 256, 0, stream>>>(hiddens, Wa1, hp);

  for (int t = 0; t < 64; t++) {
    k_q<<<4096, 256, 0, stream>>>(h1, Wa1, q);
    k_scores<<<4096, 256, 0, stream>>>(hp, q, ba1, Wa2, ba2, lengths, scores);
    k_smcvec<<<dim3(32, 2), 512, 0, stream>>>(scores, hiddens, cvp);
    k_buildx0<<<384, 256, 0, stream>>>(inputs, cvp, h0, t, xcat0);
    k_skinny<<<dim3(32, 8), 256, 0, stream>>>(xcat0, 3072, W_ih0, 2560, W_hh0, 512, 2560, 6, part, 2048);
    k_act0<<<64, 256, 0, stream>>>(part, b_ih0, b_hh0, c0, h0, h1, xcat1);
    k_skinny<<<dim3(32, 8), 256, 0, stream>>>(xcat1, 1024, W_ih1, 512, W_hh1, 512, 512, 2, part, 2048);
    k_act1<<<64, 256, 0, stream>>>(part, b_ih1, b_hh1, c1, h1, xcat0, xo);
    k_o1<<<4096, 256, 0, stream>>>(xo, Wo1, bo1, o1b);
    k_out<<<4096, 256, 0, stream>>>(o1b, Wo2, bo2, outp, t);
  }
}